// Round 14
// baseline (130.565 us; speedup 1.0000x reference)
//
#include <hip/hip_runtime.h>
#include <stdint.h>

#define B_ 16
#define H_ 128
#define W_ 128
#define C_ 128
#define F_ 64
#define N_ (H_*W_)          // 16384
#define SPLITS 64
#define RPB (N_/SPLITS)     // 256 rows per block
#define CH 64               // rows per chunk in kS
#define NCH (RPB/CH)        // 4 chunks
#define EPSV 1e-3f

typedef __attribute__((ext_vector_type(8))) short bf16x8;
typedef __attribute__((ext_vector_type(16))) float f32x16;

__device__ __forceinline__ unsigned short f2b(float f) {
    unsigned int x = __float_as_uint(f);
    x += 0x7fffu + ((x >> 16) & 1u);
    return (unsigned short)(x >> 16);
}
__device__ __forceinline__ float b2f(unsigned short u) {
    return __uint_as_float(((unsigned int)u) << 16);
}

// ---------------------------------------------------------------------------
// Kernel S v9: v8 body byte-identical; SPLITS 32->64 (grid 1024 blocks).
// ws is 512 MiB (poison-fill evidence) so the doubled Spart (64 MiB) fits.
// 3 blocks/CU resident (LDS 54KB x 3 = 159KB) = 12 waves/CU, +50% latency
// hiding vs the 2-block/CU plateau every prior structural probe kept.
// ---------------------------------------------------------------------------
__global__ __launch_bounds__(256, 3)
void kS(const float* __restrict__ x, const float* __restrict__ Wg,
        const float* __restrict__ bg, unsigned short* __restrict__ g,
        float* __restrict__ Spart, float* __restrict__ cspart)
{
    __shared__ unsigned int  xsT_hi[C_][36];                   // 18 KiB
    __shared__ unsigned int  xsT_lo[C_][36];                   // 18 KiB
    // overlay: WgT[f][c] during prologue, xs_hi[n][c] during main loop
    __shared__ __align__(16) unsigned short xs_pool[CH][136];  // 17 KiB
    __shared__ __align__(16) unsigned short gT[CH][72];        //  9 KiB

    const int tid  = threadIdx.x;
    const int lane = tid & 63;
    const int w    = tid >> 6;
    const int b    = blockIdx.x >> 6;        // / SPLITS
    const int sp   = blockIdx.x & 63;        // % SPLITS

    const float* xb = x + ((size_t)b * N_ + (size_t)sp * RPB) * C_;
    unsigned short* gb = g + ((size_t)b * N_ + (size_t)sp * RPB) * F_;

    const int rowA = lane & 31;
    const int hiL  = lane >> 5;
    const int kgrp = hiL * 8;
    const int c1b  = (w & 1) * 64;
    const int c2b  = (w >> 1) * 64;
    const int nbG  = (w & 1) * 32;
    const int fbG  = (w >> 1) * 32;

    const float bgl = bg[fbG + rowA];

    // stage WgT (bf16) into the pool, then lift this lane's frags to regs
    for (int i = tid; i < C_*F_; i += 256) {
        int c = i >> 6, f = i & 63;
        xs_pool[f][c] = f2b(Wg[i]);
    }
    __syncthreads();
    bf16x8 wgfr[8];
    #pragma unroll
    for (int ks = 0; ks < 8; ++ks)
        wgfr[ks] = *(const bf16x8*)&xs_pool[fbG + rowA][ks*16 + kgrp];
    __syncthreads();   // frag reads done before pool becomes xs_hi

    f32x16 accS[2][2];
    #pragma unroll
    for (int ti = 0; ti < 2; ++ti)
        #pragma unroll
        for (int tj = 0; tj < 2; ++tj)
            #pragma unroll
            for (int e = 0; e < 16; ++e) accS[ti][tj][e] = 0.f;

    // per-thread channel partial sums: csr[p] covers channels 4*(2w+h+8p)+k
    float4 csr[4];
    #pragma unroll
    for (int p = 0; p < 4; ++p) csr[p] = make_float4(0.f, 0.f, 0.f, 0.f);

    // coalesced g store-phase indices
    const int sr = tid >> 2;        // 0..63
    const int sc = (tid & 3) * 16;  // 0,16,32,48

    // S-read swizzle term: (((row>>3)&3)<<2), row = (mult of 32) + rowA
    const int swzR = ((rowA >> 3) & 3) << 2;

    float4 ra[4], rq[4];
    auto loadChunk = [&](int ch) {
        const float* xc = xb + (size_t)ch * CH * C_;
        #pragma unroll
        for (int p = 0; p < 4; ++p) {
            const int idx = tid + 256*p;
            const float* r0 = xc + (size_t)(2*(idx & 31)) * C_ + ((idx >> 5) * 4);
            ra[p] = *(const float4*)r0;
            rq[p] = *(const float4*)(r0 + C_);
        }
    };

    loadChunk(0);   // prologue issue; drained at first barrier A

    for (int ch = 0; ch < NCH; ++ch) {
        __syncthreads();   // (A) prior readers done; drains this chunk's loads

        // read PREVIOUS chunk's g tile into regs (gT written in gPhase(ch-1))
        uint4 gv0, gv1;
        if (ch) {
            gv0 = *(const uint4*)&gT[sr][sc];
            gv1 = *(const uint4*)&gT[sr][sc + 8];
        }

        // ---- convert + swizzled LDS store + register csum ----
        #pragma unroll
        for (int p = 0; p < 4; ++p) {
            const int idx = tid + 256*p;
            const int np  = idx & 31;
            const int c4  = (idx >> 5) * 4;
            // write-side swizzle: same for k=0..3 ((c4+k)>>3 == c4>>3 here)
            const int npx = np ^ (((c4 >> 3) & 3) << 2);
            float4 a = ra[p], q = rq[p];
            csr[p].x += a.x + q.x;
            csr[p].y += a.y + q.y;
            csr[p].z += a.z + q.z;
            csr[p].w += a.w + q.w;
            unsigned short ha0 = f2b(a.x), ha1 = f2b(a.y), ha2 = f2b(a.z), ha3 = f2b(a.w);
            unsigned short hb0 = f2b(q.x), hb1 = f2b(q.y), hb2 = f2b(q.z), hb3 = f2b(q.w);
            unsigned short la0 = f2b(a.x - b2f(ha0)), la1 = f2b(a.y - b2f(ha1));
            unsigned short la2 = f2b(a.z - b2f(ha2)), la3 = f2b(a.w - b2f(ha3));
            unsigned short lb0 = f2b(q.x - b2f(hb0)), lb1 = f2b(q.y - b2f(hb1));
            unsigned short lb2 = f2b(q.z - b2f(hb2)), lb3 = f2b(q.w - b2f(hb3));
            xsT_hi[c4+0][npx] = (unsigned)ha0 | ((unsigned)hb0 << 16);
            xsT_hi[c4+1][npx] = (unsigned)ha1 | ((unsigned)hb1 << 16);
            xsT_hi[c4+2][npx] = (unsigned)ha2 | ((unsigned)hb2 << 16);
            xsT_hi[c4+3][npx] = (unsigned)ha3 | ((unsigned)hb3 << 16);
            xsT_lo[c4+0][npx] = (unsigned)la0 | ((unsigned)lb0 << 16);
            xsT_lo[c4+1][npx] = (unsigned)la1 | ((unsigned)lb1 << 16);
            xsT_lo[c4+2][npx] = (unsigned)la2 | ((unsigned)lb2 << 16);
            xsT_lo[c4+3][npx] = (unsigned)la3 | ((unsigned)lb3 << 16);
            ushort4 u0; u0.x = ha0; u0.y = ha1; u0.z = ha2; u0.w = ha3;
            ushort4 u1; u1.x = hb0; u1.y = hb1; u1.z = hb2; u1.w = hb3;
            *(ushort4*)&xs_pool[2*np  ][c4] = u0;
            *(ushort4*)&xs_pool[2*np+1][c4] = u1;
        }

        // coalesced store of previous chunk's g tile (retires by barrier B)
        if (ch) {
            unsigned short* dst = gb + (size_t)((ch-1)*CH + sr) * F_ + sc;
            *(uint4*)dst       = gv0;
            *(uint4*)(dst + 8) = gv1;
        }
        __syncthreads();   // (B) xsT/pool writes visible

        // ---- prefetch next chunk: covered by gPhase+sPhase below ----
        if (ch < NCH - 1) loadChunk(ch + 1);

        // ---- g phase: MFMA, write tile to gT (LDS) ----
        {
            f32x16 aG;
            #pragma unroll
            for (int e = 0; e < 16; ++e) aG[e] = 0.f;
            #pragma unroll
            for (int ks = 0; ks < 8; ++ks) {
                bf16x8 av = *(const bf16x8*)&xs_pool[nbG + rowA][ks*16 + kgrp];
                aG = __builtin_amdgcn_mfma_f32_32x32x16_bf16(av, wgfr[ks], aG, 0, 0, 0);
            }
            const int fcol = fbG + rowA;
            #pragma unroll
            for (int r = 0; r < 16; ++r) {
                int nloc = (r & 3) + 8*(r >> 2) + 4*hiL;
                gT[nbG + nloc][fcol] = f2b(aG[r] + bgl);
            }
        }

        // ---- S phase: swizzled b128 reads (conflict-free) ----
        #pragma unroll
        for (int ks = 0; ks < 4; ++ks) {
            const int ro = 2 * ((8*ks + 4*hiL) ^ swzR);
            bf16x8 Ah[2], Al[2], Bh[2], Bl[2];
            #pragma unroll
            for (int t = 0; t < 2; ++t) {
                const unsigned short* rAh = (const unsigned short*)&xsT_hi[c1b + 32*t + rowA][0];
                const unsigned short* rAl = (const unsigned short*)&xsT_lo[c1b + 32*t + rowA][0];
                Ah[t] = *(const bf16x8*)(rAh + ro);
                Al[t] = *(const bf16x8*)(rAl + ro);
                const unsigned short* rBh = (const unsigned short*)&xsT_hi[c2b + 32*t + rowA][0];
                const unsigned short* rBl = (const unsigned short*)&xsT_lo[c2b + 32*t + rowA][0];
                Bh[t] = *(const bf16x8*)(rBh + ro);
                Bl[t] = *(const bf16x8*)(rBl + ro);
            }
            #pragma unroll
            for (int ti = 0; ti < 2; ++ti)
                #pragma unroll
                for (int tj = 0; tj < 2; ++tj) {
                    accS[ti][tj] = __builtin_amdgcn_mfma_f32_32x32x16_bf16(Ah[ti], Bh[tj], accS[ti][tj], 0, 0, 0);
                    accS[ti][tj] = __builtin_amdgcn_mfma_f32_32x32x16_bf16(Ah[ti], Bl[tj], accS[ti][tj], 0, 0, 0);
                    accS[ti][tj] = __builtin_amdgcn_mfma_f32_32x32x16_bf16(Al[ti], Bh[tj], accS[ti][tj], 0, 0, 0);
                }
        }
    }

    // ---- store final chunk's g tile ----
    __syncthreads();
    {
        uint4 gv0 = *(const uint4*)&gT[sr][sc];
        uint4 gv1 = *(const uint4*)&gT[sr][sc + 8];
        unsigned short* dst = gb + (size_t)((NCH - 1)*CH + sr) * F_ + sc;
        *(uint4*)dst       = gv0;
        *(uint4*)(dst + 8) = gv1;
    }

    float* so = Spart + (size_t)(b * SPLITS + sp) * (size_t)(C_ * C_);
    #pragma unroll
    for (int ti = 0; ti < 2; ++ti)
        #pragma unroll
        for (int tj = 0; tj < 2; ++tj)
            #pragma unroll
            for (int r = 0; r < 16; ++r) {
                int c1 = c1b + 32*ti + (r & 3) + 8*(r >> 2) + 4*hiL;
                int c2 = c2b + 32*tj + rowA;
                so[(size_t)c1 * C_ + c2] = accS[ti][tj][r];
            }

    // ---- csum reduction: 32-lane-half shuffle tree, lane 0/32 writes ----
    #pragma unroll
    for (int p = 0; p < 4; ++p) {
        #pragma unroll
        for (int o = 16; o; o >>= 1) {
            csr[p].x += __shfl_xor(csr[p].x, o);
            csr[p].y += __shfl_xor(csr[p].y, o);
            csr[p].z += __shfl_xor(csr[p].z, o);
            csr[p].w += __shfl_xor(csr[p].w, o);
        }
    }
    if ((lane & 31) == 0) {
        const int h = lane >> 5;
        float* co = cspart + (size_t)(b * SPLITS + sp) * C_;
        #pragma unroll
        for (int p = 0; p < 4; ++p) {
            const int c4 = 4 * (2*w + h + 8*p);
            co[c4+0] = csr[p].x;
            co[c4+1] = csr[p].y;
            co[c4+2] = csr[p].z;
            co[c4+3] = csr[p].w;
        }
    }
}

// ---------------------------------------------------------------------------
// Kernel R: reduce Spart over SPLITS -> Sred ; cspart -> csred. Pure BW.
// ---------------------------------------------------------------------------
__global__ __launch_bounds__(256, 8)
void kR(const float* __restrict__ Spart, const float* __restrict__ cspart,
        float* __restrict__ Sred, float* __restrict__ csred)
{
    const int b = blockIdx.x >> 4;
    const int r = blockIdx.x & 15;
    const int f4 = r*256 + threadIdx.x;
    const float4* base = (const float4*)(Spart + (size_t)b * SPLITS * C_ * C_);
    float sx=0.f, sy=0.f, sz=0.f, sw=0.f;
    #pragma unroll 4
    for (int sp = 0; sp < SPLITS; ++sp) {
        float4 v = base[(size_t)sp * (C_*C_/4) + f4];
        sx += v.x; sy += v.y; sz += v.z; sw += v.w;
    }
    ((float4*)(Sred + (size_t)b * C_ * C_))[f4] = make_float4(sx, sy, sz, sw);

    if (r == 0 && threadIdx.x < C_) {
        float c = 0.f;
        #pragma unroll 4
        for (int sp = 0; sp < SPLITS; ++sp)
            c += cspart[((size_t)b * SPLITS + sp) * C_ + threadIdx.x];
        csred[(size_t)b * C_ + threadIdx.x] = c;
    }
}

// ---------------------------------------------------------------------------
// Kernel T: T1 = S @ Wp (per-batch 128x64, K=128), LDS-staged; also T2 = cs@Wp.
// ---------------------------------------------------------------------------
__global__ __launch_bounds__(256, 2)
void kT(const float* __restrict__ Sred, const float* __restrict__ csred,
        const float* __restrict__ Wp, float* __restrict__ T1buf,
        float* __restrict__ T2buf)
{
    __shared__ float Ss[32][C_];
    __shared__ float Wps[C_][F_];

    const int tid = threadIdx.x;
    const int b = blockIdx.x >> 2;
    const int q = blockIdx.x & 3;

    const float4* sg = (const float4*)(Sred + ((size_t)b * C_ + q*32) * C_);
    for (int t = tid; t < 32*C_/4; t += 256) ((float4*)Ss)[t] = sg[t];
    const float4* wg = (const float4*)Wp;
    for (int t = tid; t < C_*F_/4; t += 256) ((float4*)Wps)[t] = wg[t];
    __syncthreads();

    const int lane = tid & 63;
    const int w    = tid >> 6;

    float acc[8] = {0.f,0.f,0.f,0.f,0.f,0.f,0.f,0.f};
    #pragma unroll 2
    for (int k = 0; k < C_; k += 4) {
        float w0 = Wps[k+0][lane];
        float w1 = Wps[k+1][lane];
        float w2 = Wps[k+2][lane];
        float w3 = Wps[k+3][lane];
        #pragma unroll
        for (int cl = 0; cl < 8; ++cl) {
            float4 sv = *(const float4*)&Ss[w*8 + cl][k];
            float t = acc[cl];
            t = fmaf(sv.x, w0, t);
            t = fmaf(sv.y, w1, t);
            t = fmaf(sv.z, w2, t);
            t = fmaf(sv.w, w3, t);
            acc[cl] = t;
        }
    }
    #pragma unroll
    for (int cl = 0; cl < 8; ++cl) {
        int c = q*32 + w*8 + cl;
        T1buf[((size_t)b * C_ + c) * F_ + lane] = acc[cl];
    }

    if (q == 0 && tid < F_) {
        const float* cv = csred + (size_t)b * C_;
        float s = 0.f;
        for (int k = 0; k < C_; ++k) s = fmaf(cv[k], Wps[k][tid], s);
        T2buf[(size_t)b * F_ + tid] = s;
    }
}

// ---------------------------------------------------------------------------
// Kernel F: fm = Wt^T T1 + bias terms; in-register row softmax -> U.
// ---------------------------------------------------------------------------
__global__ __launch_bounds__(256, 2)
void kF(const float* __restrict__ T1buf, const float* __restrict__ T2buf,
        const float* __restrict__ csred, const float* __restrict__ Wt,
        const float* __restrict__ bt, const float* __restrict__ bp,
        float* __restrict__ U)
{
    __shared__ float T1s[C_][F_];
    __shared__ float Wts[C_][F_];
    __shared__ float csb[C_];
    __shared__ float T2s[F_], T3s[F_], bts[F_], bps[F_];

    const int tid = threadIdx.x;
    const int b = blockIdx.x;

    for (int t = tid; t < C_*F_/4; t += 256) {
        ((float4*)T1s)[t] = ((const float4*)(T1buf + (size_t)b * C_ * F_))[t];
        ((float4*)Wts)[t] = ((const float4*)Wt)[t];
    }
    if (tid < C_) csb[tid] = csred[(size_t)b * C_ + tid];
    if (tid < F_) {
        T2s[tid] = T2buf[(size_t)b * F_ + tid];
        bts[tid] = bt[tid];
        bps[tid] = bp[tid];
    }
    __syncthreads();

    if (tid < F_) {
        float s = 0.f;
        for (int c = 0; c < C_; ++c) s = fmaf(csb[c], Wts[c][tid], s);
        T3s[tid] = s;
    }
    __syncthreads();

    const int lane = tid & 63;
    const int w    = tid >> 6;

    float acc[16];
    #pragma unroll
    for (int r = 0; r < 16; ++r) acc[r] = 0.f;

    #pragma unroll 2
    for (int c = 0; c < C_; ++c) {
        float t1 = T1s[c][lane];
        #pragma unroll
        for (int u = 0; u < 4; ++u) {
            float4 wv = *(const float4*)&Wts[c][w*16 + u*4];
            acc[u*4+0] = fmaf(wv.x, t1, acc[u*4+0]);
            acc[u*4+1] = fmaf(wv.y, t1, acc[u*4+1]);
            acc[u*4+2] = fmaf(wv.z, t1, acc[u*4+2]);
            acc[u*4+3] = fmaf(wv.w, t1, acc[u*4+3]);
        }
    }

    const float bpj = bps[lane];
    const float t2j = T2s[lane];
    #pragma unroll
    for (int r = 0; r < 16; ++r) {
        const int i = w*16 + r;
        float v = acc[r] + T3s[i]*bpj + bts[i]*(t2j + (float)N_ * bpj);
        float m = v;
        #pragma unroll
        for (int o = 32; o; o >>= 1) m = fmaxf(m, __shfl_xor(m, o));
        float e = expf(v - m);
        float s = e;
        #pragma unroll
        for (int o = 32; o; o >>= 1) s += __shfl_xor(s, o);
        U[((size_t)b * F_ + i) * F_ + lane] = e / s;
    }
}

// ---------------------------------------------------------------------------
// Kernel C (MFMA, conservative): per (b,half,w): M1 = G_w @ U ;
// Out = M1^T @ Wo ; bias+BN fused. M1 acc -> A-operand relayout through a
// wave-private LDS strip using f2b bit-packing and full __syncthreads fences.
// ---------------------------------------------------------------------------
__global__ __launch_bounds__(256, 2)
void kC(const unsigned short* __restrict__ g, const float* __restrict__ U,
        const float* __restrict__ Wo, const float* __restrict__ bo,
        const float* __restrict__ gamma_, const float* __restrict__ beta_,
        const float* __restrict__ mmean, const float* __restrict__ mvar,
        float* __restrict__ out)
{
    __shared__ __align__(16) unsigned short UT[F_][72];        // UT[j][i] bf16
    __shared__ __align__(16) unsigned short WoT[F_][72];       // WoT[e'][f] bf16
    __shared__ __align__(16) unsigned short M1T[4][32][72];    // per-wave M1^T[j][e]

    const int tid  = threadIdx.x;
    const int lane = tid & 63;
    const int wv   = tid >> 6;
    const int jt   = wv & 1;
    const int et   = wv >> 1;

    const int wgrp = blockIdx.x & 15;
    const int half = (blockIdx.x >> 4) & 1;
    const int b    = blockIdx.x >> 5;

    for (int t = tid; t < 1024; t += 256) {
        const int i  = t >> 4;
        const int j4 = (t & 15) * 4;
        float4 uv = *(const float4*)(U + ((size_t)b * F_ + i) * F_ + j4);
        UT[j4+0][i] = f2b(uv.x); UT[j4+1][i] = f2b(uv.y);
        UT[j4+2][i] = f2b(uv.z); UT[j4+3][i] = f2b(uv.w);
        float4 wo4 = *(const float4*)(Wo + (size_t)i * F_ + j4);
        WoT[j4+0][i] = f2b(wo4.x); WoT[j4+1][i] = f2b(wo4.y);
        WoT[j4+2][i] = f2b(wo4.z); WoT[j4+3][i] = f2b(wo4.w);
    }
    __syncthreads();

    const int rowA = lane & 31;
    const int hi   = lane >> 5;
    const int hi8  = hi * 8;

    bf16x8 Ufr[4], WoFr[4];
    #pragma unroll
    for (int ks = 0; ks < 4; ++ks) {
        Ufr[ks]  = *(const bf16x8*)&UT [32*jt + rowA][16*ks + hi8];
        WoFr[ks] = *(const bf16x8*)&WoT[32*et + rowA][16*ks + hi8];
    }

    const int ep = 32*et + rowA;                 // this lane's output channel
    const float scl = gamma_[ep] * rsqrtf(mvar[ep] + EPSV);
    const float sft = (bo[ep] - mmean[ep]) * scl + beta_[ep];

    const unsigned short* gB = g + ((size_t)b * N_ + (size_t)half * (N_/2)) * F_;
    float* outB = out + (((size_t)b * H_ + half) * W_) * F_ + ep;
    const int w0 = wgrp * 8;

    unsigned short* m1row = &M1T[wv][rowA][0];

    auto gload = [&](bf16x8 (&D)[2][4], int widx) {
        const unsigned short* gw = gB + (size_t)widx * (64*F_) + (size_t)rowA * F_ + hi8;
        #pragma unroll
        for (int ft = 0; ft < 2; ++ft)
            #pragma unroll
            for (int ks = 0; ks < 4; ++ks)
                D[ft][ks] = *(const bf16x8*)(gw + ft*(32*F_) + 16*ks);
    };

    auto body = [&](bf16x8 (&G)[2][4], int widx) {
        f32x16 m0, m1, a2r;
        #pragma unroll
        for (int e = 0; e < 16; ++e) { m0[e] = 0.f; m1[e] = 0.f; a2r[e] = 0.f; }
        #pragma unroll
        for (int ks = 0; ks < 4; ++ks) {
            m0 = __builtin_amdgcn_mfma_f32_32x32x16_bf16(G[0][ks], Ufr[ks], m0, 0, 0, 0);
            m1 = __builtin_amdgcn_mfma_f32_32x32x16_bf16(G[1][ks], Ufr[ks], m1, 0, 0, 0);
        }
        #pragma unroll
        for (int r = 0; r < 16; r += 2) {
            const int e0 = (r & 3) + 8*(r >> 2) + 4*hi;
            const unsigned pw0 = (unsigned)f2b(m0[r]) | ((unsigned)f2b(m0[r+1]) << 16);
            *(unsigned int*)(m1row + e0) = pw0;
            const unsigned pw1 = (unsigned)f2b(m1[r]) | ((unsigned)f2b(m1[r+1]) << 16);
            *(unsigned int*)(m1row + 32 + e0) = pw1;
        }
        __syncthreads();
        #pragma unroll
        for (int ksg = 0; ksg < 4; ++ksg) {
            bf16x8 af = *(const bf16x8*)(m1row + 16*ksg + hi8);
            a2r = __builtin_amdgcn_mfma_f32_32x32x16_bf16(af, WoFr[ksg], a2r, 0, 0, 0);
        }
        float* ow = outB + (size_t)widx * F_ + (size_t)(64*jt + 8*hi) * (W_*F_);
        #pragma unroll
        for (int r = 0; r < 16; ++r) {
            const int off2j = 2*(r & 3) + 16*(r >> 2);   // 2*j within quad
            ow[(size_t)off2j * (W_*F_)] = a2r[r] * scl + sft;
        }
        __syncthreads();
    };

    bf16x8 GA[2][4], GBf[2][4];
    gload(GA, w0);
    #pragma unroll
    for (int wi = 0; wi < 8; ++wi) {
        if (wi & 1) {
            if (wi < 7) gload(GA, w0 + wi + 1);
            body(GBf, w0 + wi);
        } else {
            if (wi < 7) gload(GBf, w0 + wi + 1);
            body(GA, w0 + wi);
        }
    }
}

extern "C" void kernel_launch(void* const* d_in, const int* in_sizes, int n_in,
                              void* d_out, int out_size, void* d_ws, size_t ws_size,
                              hipStream_t stream)
{
    const float* x  = (const float*)d_in[0];
    const float* Wg = (const float*)d_in[1];
    const float* bg = (const float*)d_in[2];
    const float* Wt = (const float*)d_in[3];
    const float* bt = (const float*)d_in[4];
    const float* Wp = (const float*)d_in[5];
    const float* bp = (const float*)d_in[6];
    const float* Wo = (const float*)d_in[7];
    const float* bo = (const float*)d_in[8];
    const float* ga = (const float*)d_in[9];
    const float* be = (const float*)d_in[10];
    const float* mm = (const float*)d_in[11];
    const float* mv = (const float*)d_in[12];
    float* out = (float*)d_out;

    // ws layout: g 32MiB | Spart 64MiB (T1buf overlays; Spart dead after kR) |
    //            cspart 512KiB | U 256KiB | Sred 1MiB | csred 8KiB | T2buf 4KiB
    char* ws = (char*)d_ws;
    unsigned short* g = (unsigned short*)ws;
    size_t off = (size_t)B_ * N_ * F_ * sizeof(unsigned short);
    float* Spart = (float*)(ws + off);
    float* T1buf = (float*)(ws + off);
    off += (size_t)B_ * SPLITS * C_ * C_ * sizeof(float);
    float* cspart = (float*)(ws + off);
    off += (size_t)B_ * SPLITS * C_ * sizeof(float);
    float* U = (float*)(ws + off);
    off += (size_t)B_ * F_ * F_ * sizeof(float);
    float* Sred = (float*)(ws + off);
    off += (size_t)B_ * C_ * C_ * sizeof(float);
    float* csred = (float*)(ws + off);
    off += (size_t)B_ * C_ * sizeof(float);
    float* T2buf = (float*)(ws + off);

    kS<<<B_ * SPLITS, 256, 0, stream>>>(x, Wg, bg, g, Spart, cspart);
    kR<<<B_ * 16, 256, 0, stream>>>(Spart, cspart, Sred, csred);
    kT<<<B_ * 4, 256, 0, stream>>>(Sred, csred, Wp, T1buf, T2buf);
    kF<<<B_, 256, 0, stream>>>(T1buf, T2buf, csred, Wt, bt, bp, U);
    kC<<<B_ * 2 * (W_/8), 256, 0, stream>>>(g, U, Wo, bo, ga, be, mm, mv, out);
}

// Round 15
// 106.370 us; speedup vs baseline: 1.2275x; 1.2275x over previous
//
#include <hip/hip_runtime.h>
#include <stdint.h>

#define B_ 16
#define H_ 128
#define W_ 128
#define C_ 128
#define F_ 64
#define N_ (H_*W_)          // 16384
#define SPLITS 32
#define RPB (N_/SPLITS)     // 512 rows per block
#define CH 64               // rows per chunk in kS
#define NCH (RPB/CH)        // 8 chunks
#define EPSV 1e-3f

typedef __attribute__((ext_vector_type(8))) short bf16x8;
typedef __attribute__((ext_vector_type(16))) float f32x16;

__device__ __forceinline__ unsigned short f2b(float f) {
    unsigned int x = __float_as_uint(f);
    x += 0x7fffu + ((x >> 16) & 1u);
    return (unsigned short)(x >> 16);
}
__device__ __forceinline__ float b2f(unsigned short u) {
    return __uint_as_float(((unsigned int)u) << 16);
}

// ---------------------------------------------------------------------------
// Kernel S v8 (round-13 verbatim, 106.9us build): register csum, prefetch
// after barrier B, XOR word-swizzle on xsT, gT-coalesced g stores.
// ---------------------------------------------------------------------------
__global__ __launch_bounds__(256, 2)
void kS(const float* __restrict__ x, const float* __restrict__ Wg,
        const float* __restrict__ bg, unsigned short* __restrict__ g,
        float* __restrict__ Spart, float* __restrict__ cspart)
{
    __shared__ unsigned int  xsT_hi[C_][36];                   // 18 KiB
    __shared__ unsigned int  xsT_lo[C_][36];                   // 18 KiB
    __shared__ __align__(16) unsigned short xs_pool[CH][136];  // 17 KiB
    __shared__ __align__(16) unsigned short gT[CH][72];        //  9 KiB

    const int tid  = threadIdx.x;
    const int lane = tid & 63;
    const int w    = tid >> 6;
    const int b    = blockIdx.x >> 5;
    const int sp   = blockIdx.x & 31;

    const float* xb = x + ((size_t)b * N_ + (size_t)sp * RPB) * C_;
    unsigned short* gb = g + ((size_t)b * N_ + (size_t)sp * RPB) * F_;

    const int rowA = lane & 31;
    const int hiL  = lane >> 5;
    const int kgrp = hiL * 8;
    const int c1b  = (w & 1) * 64;
    const int c2b  = (w >> 1) * 64;
    const int nbG  = (w & 1) * 32;
    const int fbG  = (w >> 1) * 32;

    const float bgl = bg[fbG + rowA];

    for (int i = tid; i < C_*F_; i += 256) {
        int c = i >> 6, f = i & 63;
        xs_pool[f][c] = f2b(Wg[i]);
    }
    __syncthreads();
    bf16x8 wgfr[8];
    #pragma unroll
    for (int ks = 0; ks < 8; ++ks)
        wgfr[ks] = *(const bf16x8*)&xs_pool[fbG + rowA][ks*16 + kgrp];
    __syncthreads();   // frag reads done before pool becomes xs_hi

    f32x16 accS[2][2];
    #pragma unroll
    for (int ti = 0; ti < 2; ++ti)
        #pragma unroll
        for (int tj = 0; tj < 2; ++tj)
            #pragma unroll
            for (int e = 0; e < 16; ++e) accS[ti][tj][e] = 0.f;

    float4 csr[4];
    #pragma unroll
    for (int p = 0; p < 4; ++p) csr[p] = make_float4(0.f, 0.f, 0.f, 0.f);

    const int sr = tid >> 2;        // 0..63
    const int sc = (tid & 3) * 16;  // 0,16,32,48

    const int swzR = ((rowA >> 3) & 3) << 2;

    float4 ra[4], rq[4];
    auto loadChunk = [&](int ch) {
        const float* xc = xb + (size_t)ch * CH * C_;
        #pragma unroll
        for (int p = 0; p < 4; ++p) {
            const int idx = tid + 256*p;
            const float* r0 = xc + (size_t)(2*(idx & 31)) * C_ + ((idx >> 5) * 4);
            ra[p] = *(const float4*)r0;
            rq[p] = *(const float4*)(r0 + C_);
        }
    };

    loadChunk(0);

    for (int ch = 0; ch < NCH; ++ch) {
        __syncthreads();   // (A) prior readers done; drains this chunk's loads

        uint4 gv0, gv1;
        if (ch) {
            gv0 = *(const uint4*)&gT[sr][sc];
            gv1 = *(const uint4*)&gT[sr][sc + 8];
        }

        #pragma unroll
        for (int p = 0; p < 4; ++p) {
            const int idx = tid + 256*p;
            const int np  = idx & 31;
            const int c4  = (idx >> 5) * 4;
            const int npx = np ^ (((c4 >> 3) & 3) << 2);
            float4 a = ra[p], q = rq[p];
            csr[p].x += a.x + q.x;
            csr[p].y += a.y + q.y;
            csr[p].z += a.z + q.z;
            csr[p].w += a.w + q.w;
            unsigned short ha0 = f2b(a.x), ha1 = f2b(a.y), ha2 = f2b(a.z), ha3 = f2b(a.w);
            unsigned short hb0 = f2b(q.x), hb1 = f2b(q.y), hb2 = f2b(q.z), hb3 = f2b(q.w);
            unsigned short la0 = f2b(a.x - b2f(ha0)), la1 = f2b(a.y - b2f(ha1));
            unsigned short la2 = f2b(a.z - b2f(ha2)), la3 = f2b(a.w - b2f(ha3));
            unsigned short lb0 = f2b(q.x - b2f(hb0)), lb1 = f2b(q.y - b2f(hb1));
            unsigned short lb2 = f2b(q.z - b2f(hb2)), lb3 = f2b(q.w - b2f(hb3));
            xsT_hi[c4+0][npx] = (unsigned)ha0 | ((unsigned)hb0 << 16);
            xsT_hi[c4+1][npx] = (unsigned)ha1 | ((unsigned)hb1 << 16);
            xsT_hi[c4+2][npx] = (unsigned)ha2 | ((unsigned)hb2 << 16);
            xsT_hi[c4+3][npx] = (unsigned)ha3 | ((unsigned)hb3 << 16);
            xsT_lo[c4+0][npx] = (unsigned)la0 | ((unsigned)lb0 << 16);
            xsT_lo[c4+1][npx] = (unsigned)la1 | ((unsigned)lb1 << 16);
            xsT_lo[c4+2][npx] = (unsigned)la2 | ((unsigned)lb2 << 16);
            xsT_lo[c4+3][npx] = (unsigned)la3 | ((unsigned)lb3 << 16);
            ushort4 u0; u0.x = ha0; u0.y = ha1; u0.z = ha2; u0.w = ha3;
            ushort4 u1; u1.x = hb0; u1.y = hb1; u1.z = hb2; u1.w = hb3;
            *(ushort4*)&xs_pool[2*np  ][c4] = u0;
            *(ushort4*)&xs_pool[2*np+1][c4] = u1;
        }

        if (ch) {
            unsigned short* dst = gb + (size_t)((ch-1)*CH + sr) * F_ + sc;
            *(uint4*)dst       = gv0;
            *(uint4*)(dst + 8) = gv1;
        }
        __syncthreads();   // (B) xsT/pool writes visible

        if (ch < NCH - 1) loadChunk(ch + 1);

        {
            f32x16 aG;
            #pragma unroll
            for (int e = 0; e < 16; ++e) aG[e] = 0.f;
            #pragma unroll
            for (int ks = 0; ks < 8; ++ks) {
                bf16x8 av = *(const bf16x8*)&xs_pool[nbG + rowA][ks*16 + kgrp];
                aG = __builtin_amdgcn_mfma_f32_32x32x16_bf16(av, wgfr[ks], aG, 0, 0, 0);
            }
            const int fcol = fbG + rowA;
            #pragma unroll
            for (int r = 0; r < 16; ++r) {
                int nloc = (r & 3) + 8*(r >> 2) + 4*hiL;
                gT[nbG + nloc][fcol] = f2b(aG[r] + bgl);
            }
        }

        #pragma unroll
        for (int ks = 0; ks < 4; ++ks) {
            const int ro = 2 * ((8*ks + 4*hiL) ^ swzR);
            bf16x8 Ah[2], Al[2], Bh[2], Bl[2];
            #pragma unroll
            for (int t = 0; t < 2; ++t) {
                const unsigned short* rAh = (const unsigned short*)&xsT_hi[c1b + 32*t + rowA][0];
                const unsigned short* rAl = (const unsigned short*)&xsT_lo[c1b + 32*t + rowA][0];
                Ah[t] = *(const bf16x8*)(rAh + ro);
                Al[t] = *(const bf16x8*)(rAl + ro);
                const unsigned short* rBh = (const unsigned short*)&xsT_hi[c2b + 32*t + rowA][0];
                const unsigned short* rBl = (const unsigned short*)&xsT_lo[c2b + 32*t + rowA][0];
                Bh[t] = *(const bf16x8*)(rBh + ro);
                Bl[t] = *(const bf16x8*)(rBl + ro);
            }
            #pragma unroll
            for (int ti = 0; ti < 2; ++ti)
                #pragma unroll
                for (int tj = 0; tj < 2; ++tj) {
                    accS[ti][tj] = __builtin_amdgcn_mfma_f32_32x32x16_bf16(Ah[ti], Bh[tj], accS[ti][tj], 0, 0, 0);
                    accS[ti][tj] = __builtin_amdgcn_mfma_f32_32x32x16_bf16(Ah[ti], Bl[tj], accS[ti][tj], 0, 0, 0);
                    accS[ti][tj] = __builtin_amdgcn_mfma_f32_32x32x16_bf16(Al[ti], Bh[tj], accS[ti][tj], 0, 0, 0);
                }
        }
    }

    __syncthreads();
    {
        uint4 gv0 = *(const uint4*)&gT[sr][sc];
        uint4 gv1 = *(const uint4*)&gT[sr][sc + 8];
        unsigned short* dst = gb + (size_t)((NCH - 1)*CH + sr) * F_ + sc;
        *(uint4*)dst       = gv0;
        *(uint4*)(dst + 8) = gv1;
    }

    float* so = Spart + (size_t)(b * SPLITS + sp) * (size_t)(C_ * C_);
    #pragma unroll
    for (int ti = 0; ti < 2; ++ti)
        #pragma unroll
        for (int tj = 0; tj < 2; ++tj)
            #pragma unroll
            for (int r = 0; r < 16; ++r) {
                int c1 = c1b + 32*ti + (r & 3) + 8*(r >> 2) + 4*hiL;
                int c2 = c2b + 32*tj + rowA;
                so[(size_t)c1 * C_ + c2] = accS[ti][tj][r];
            }

    #pragma unroll
    for (int p = 0; p < 4; ++p) {
        #pragma unroll
        for (int o = 16; o; o >>= 1) {
            csr[p].x += __shfl_xor(csr[p].x, o);
            csr[p].y += __shfl_xor(csr[p].y, o);
            csr[p].z += __shfl_xor(csr[p].z, o);
            csr[p].w += __shfl_xor(csr[p].w, o);
        }
    }
    if ((lane & 31) == 0) {
        const int h = lane >> 5;
        float* co = cspart + (size_t)(b * SPLITS + sp) * C_;
        #pragma unroll
        for (int p = 0; p < 4; ++p) {
            const int c4 = 4 * (2*w + h + 8*p);
            co[c4+0] = csr[p].x;
            co[c4+1] = csr[p].y;
            co[c4+2] = csr[p].z;
            co[c4+3] = csr[p].w;
        }
    }
}

// ---------------------------------------------------------------------------
// Kernel R: reduce Spart over splits -> Sred ; cspart -> csred. Pure BW.
// ---------------------------------------------------------------------------
__global__ __launch_bounds__(256, 8)
void kR(const float* __restrict__ Spart, const float* __restrict__ cspart,
        float* __restrict__ Sred, float* __restrict__ csred)
{
    const int b = blockIdx.x >> 4;
    const int r = blockIdx.x & 15;
    const int f4 = r*256 + threadIdx.x;
    const float4* base = (const float4*)(Spart + (size_t)b * SPLITS * C_ * C_);
    float sx=0.f, sy=0.f, sz=0.f, sw=0.f;
    #pragma unroll 4
    for (int sp = 0; sp < SPLITS; ++sp) {
        float4 v = base[(size_t)sp * (C_*C_/4) + f4];
        sx += v.x; sy += v.y; sz += v.z; sw += v.w;
    }
    ((float4*)(Sred + (size_t)b * C_ * C_))[f4] = make_float4(sx, sy, sz, sw);

    if (r == 0 && threadIdx.x < C_) {
        float c = 0.f;
        #pragma unroll 4
        for (int sp = 0; sp < SPLITS; ++sp)
            c += cspart[((size_t)b * SPLITS + sp) * C_ + threadIdx.x];
        csred[(size_t)b * C_ + threadIdx.x] = c;
    }
}

// ---------------------------------------------------------------------------
// Kernel T: T1 = S @ Wp (per-batch 128x64, K=128), LDS-staged; also T2 = cs@Wp.
// ---------------------------------------------------------------------------
__global__ __launch_bounds__(256, 2)
void kT(const float* __restrict__ Sred, const float* __restrict__ csred,
        const float* __restrict__ Wp, float* __restrict__ T1buf,
        float* __restrict__ T2buf)
{
    __shared__ float Ss[32][C_];
    __shared__ float Wps[C_][F_];

    const int tid = threadIdx.x;
    const int b = blockIdx.x >> 2;
    const int q = blockIdx.x & 3;

    const float4* sg = (const float4*)(Sred + ((size_t)b * C_ + q*32) * C_);
    for (int t = tid; t < 32*C_/4; t += 256) ((float4*)Ss)[t] = sg[t];
    const float4* wg = (const float4*)Wp;
    for (int t = tid; t < C_*F_/4; t += 256) ((float4*)Wps)[t] = wg[t];
    __syncthreads();

    const int lane = tid & 63;
    const int w    = tid >> 6;

    float acc[8] = {0.f,0.f,0.f,0.f,0.f,0.f,0.f,0.f};
    #pragma unroll 2
    for (int k = 0; k < C_; k += 4) {
        float w0 = Wps[k+0][lane];
        float w1 = Wps[k+1][lane];
        float w2 = Wps[k+2][lane];
        float w3 = Wps[k+3][lane];
        #pragma unroll
        for (int cl = 0; cl < 8; ++cl) {
            float4 sv = *(const float4*)&Ss[w*8 + cl][k];
            float t = acc[cl];
            t = fmaf(sv.x, w0, t);
            t = fmaf(sv.y, w1, t);
            t = fmaf(sv.z, w2, t);
            t = fmaf(sv.w, w3, t);
            acc[cl] = t;
        }
    }
    #pragma unroll
    for (int cl = 0; cl < 8; ++cl) {
        int c = q*32 + w*8 + cl;
        T1buf[((size_t)b * C_ + c) * F_ + lane] = acc[cl];
    }

    if (q == 0 && tid < F_) {
        const float* cv = csred + (size_t)b * C_;
        float s = 0.f;
        for (int k = 0; k < C_; ++k) s = fmaf(cv[k], Wps[k][tid], s);
        T2buf[(size_t)b * F_ + tid] = s;
    }
}

// ---------------------------------------------------------------------------
// Kernel F: fm = Wt^T T1 + bias terms; in-register row softmax -> U.
// ---------------------------------------------------------------------------
__global__ __launch_bounds__(256, 2)
void kF(const float* __restrict__ T1buf, const float* __restrict__ T2buf,
        const float* __restrict__ csred, const float* __restrict__ Wt,
        const float* __restrict__ bt, const float* __restrict__ bp,
        float* __restrict__ U)
{
    __shared__ float T1s[C_][F_];
    __shared__ float Wts[C_][F_];
    __shared__ float csb[C_];
    __shared__ float T2s[F_], T3s[F_], bts[F_], bps[F_];

    const int tid = threadIdx.x;
    const int b = blockIdx.x;

    for (int t = tid; t < C_*F_/4; t += 256) {
        ((float4*)T1s)[t] = ((const float4*)(T1buf + (size_t)b * C_ * F_))[t];
        ((float4*)Wts)[t] = ((const float4*)Wt)[t];
    }
    if (tid < C_) csb[tid] = csred[(size_t)b * C_ + tid];
    if (tid < F_) {
        T2s[tid] = T2buf[(size_t)b * F_ + tid];
        bts[tid] = bt[tid];
        bps[tid] = bp[tid];
    }
    __syncthreads();

    if (tid < F_) {
        float s = 0.f;
        for (int c = 0; c < C_; ++c) s = fmaf(csb[c], Wts[c][tid], s);
        T3s[tid] = s;
    }
    __syncthreads();

    const int lane = tid & 63;
    const int w    = tid >> 6;

    float acc[16];
    #pragma unroll
    for (int r = 0; r < 16; ++r) acc[r] = 0.f;

    #pragma unroll 2
    for (int c = 0; c < C_; ++c) {
        float t1 = T1s[c][lane];
        #pragma unroll
        for (int u = 0; u < 4; ++u) {
            float4 wv = *(const float4*)&Wts[c][w*16 + u*4];
            acc[u*4+0] = fmaf(wv.x, t1, acc[u*4+0]);
            acc[u*4+1] = fmaf(wv.y, t1, acc[u*4+1]);
            acc[u*4+2] = fmaf(wv.z, t1, acc[u*4+2]);
            acc[u*4+3] = fmaf(wv.w, t1, acc[u*4+3]);
        }
    }

    const float bpj = bps[lane];
    const float t2j = T2s[lane];
    #pragma unroll
    for (int r = 0; r < 16; ++r) {
        const int i = w*16 + r;
        float v = acc[r] + T3s[i]*bpj + bts[i]*(t2j + (float)N_ * bpj);
        float m = v;
        #pragma unroll
        for (int o = 32; o; o >>= 1) m = fmaxf(m, __shfl_xor(m, o));
        float e = expf(v - m);
        float s = e;
        #pragma unroll
        for (int o = 32; o; o >>= 1) s += __shfl_xor(s, o);
        U[((size_t)b * F_ + i) * F_ + lane] = e / s;
    }
}

// ---------------------------------------------------------------------------
// Kernel C (MFMA): per (b,half,w): M1 = G_w @ U ; Out = M1^T @ Wo ; bias+BN.
// M1T strip is WAVE-PRIVATE (M1T[wv]); the round-6 in-body __syncthreads were
// a bisection artifact — intra-wave DS write->read ordering is compiler-
// enforced (lgkmcnt on the same LDS object). Removed: waves now run the 8-w
// loop fully independently (no 4-wave lockstep, no per-body drains).
// ---------------------------------------------------------------------------
__global__ __launch_bounds__(256, 2)
void kC(const unsigned short* __restrict__ g, const float* __restrict__ U,
        const float* __restrict__ Wo, const float* __restrict__ bo,
        const float* __restrict__ gamma_, const float* __restrict__ beta_,
        const float* __restrict__ mmean, const float* __restrict__ mvar,
        float* __restrict__ out)
{
    __shared__ __align__(16) unsigned short UT[F_][72];        // UT[j][i] bf16
    __shared__ __align__(16) unsigned short WoT[F_][72];       // WoT[e'][f] bf16
    __shared__ __align__(16) unsigned short M1T[4][32][72];    // per-wave M1^T[j][e]

    const int tid  = threadIdx.x;
    const int lane = tid & 63;
    const int wv   = tid >> 6;
    const int jt   = wv & 1;
    const int et   = wv >> 1;

    const int wgrp = blockIdx.x & 15;
    const int half = (blockIdx.x >> 4) & 1;
    const int b    = blockIdx.x >> 5;

    for (int t = tid; t < 1024; t += 256) {
        const int i  = t >> 4;
        const int j4 = (t & 15) * 4;
        float4 uv = *(const float4*)(U + ((size_t)b * F_ + i) * F_ + j4);
        UT[j4+0][i] = f2b(uv.x); UT[j4+1][i] = f2b(uv.y);
        UT[j4+2][i] = f2b(uv.z); UT[j4+3][i] = f2b(uv.w);
        float4 wo4 = *(const float4*)(Wo + (size_t)i * F_ + j4);
        WoT[j4+0][i] = f2b(wo4.x); WoT[j4+1][i] = f2b(wo4.y);
        WoT[j4+2][i] = f2b(wo4.z); WoT[j4+3][i] = f2b(wo4.w);
    }
    __syncthreads();

    const int rowA = lane & 31;
    const int hi   = lane >> 5;
    const int hi8  = hi * 8;

    bf16x8 Ufr[4], WoFr[4];
    #pragma unroll
    for (int ks = 0; ks < 4; ++ks) {
        Ufr[ks]  = *(const bf16x8*)&UT [32*jt + rowA][16*ks + hi8];
        WoFr[ks] = *(const bf16x8*)&WoT[32*et + rowA][16*ks + hi8];
    }

    const int ep = 32*et + rowA;                 // this lane's output channel
    const float scl = gamma_[ep] * rsqrtf(mvar[ep] + EPSV);
    const float sft = (bo[ep] - mmean[ep]) * scl + beta_[ep];

    const unsigned short* gB = g + ((size_t)b * N_ + (size_t)half * (N_/2)) * F_;
    float* outB = out + (((size_t)b * H_ + half) * W_) * F_ + ep;
    const int w0 = wgrp * 8;

    unsigned short* m1row = &M1T[wv][rowA][0];

    auto gload = [&](bf16x8 (&D)[2][4], int widx) {
        const unsigned short* gw = gB + (size_t)widx * (64*F_) + (size_t)rowA * F_ + hi8;
        #pragma unroll
        for (int ft = 0; ft < 2; ++ft)
            #pragma unroll
            for (int ks = 0; ks < 4; ++ks)
                D[ft][ks] = *(const bf16x8*)(gw + ft*(32*F_) + 16*ks);
    };

    auto body = [&](bf16x8 (&G)[2][4], int widx) {
        f32x16 m0, m1, a2r;
        #pragma unroll
        for (int e = 0; e < 16; ++e) { m0[e] = 0.f; m1[e] = 0.f; a2r[e] = 0.f; }
        #pragma unroll
        for (int ks = 0; ks < 4; ++ks) {
            m0 = __builtin_amdgcn_mfma_f32_32x32x16_bf16(G[0][ks], Ufr[ks], m0, 0, 0, 0);
            m1 = __builtin_amdgcn_mfma_f32_32x32x16_bf16(G[1][ks], Ufr[ks], m1, 0, 0, 0);
        }
        // wave-private strip: write M1^T (bf16) via C/D layout
        #pragma unroll
        for (int r = 0; r < 16; r += 2) {
            const int e0 = (r & 3) + 8*(r >> 2) + 4*hi;
            const unsigned pw0 = (unsigned)f2b(m0[r]) | ((unsigned)f2b(m0[r+1]) << 16);
            *(unsigned int*)(m1row + e0) = pw0;
            const unsigned pw1 = (unsigned)f2b(m1[r]) | ((unsigned)f2b(m1[r+1]) << 16);
            *(unsigned int*)(m1row + 32 + e0) = pw1;
        }
        // intra-wave DS ordering: compiler emits lgkmcnt before these reads
        #pragma unroll
        for (int ksg = 0; ksg < 4; ++ksg) {
            bf16x8 af = *(const bf16x8*)(m1row + 16*ksg + hi8);
            a2r = __builtin_amdgcn_mfma_f32_32x32x16_bf16(af, WoFr[ksg], a2r, 0, 0, 0);
        }
        float* ow = outB + (size_t)widx * F_ + (size_t)(64*jt + 8*hi) * (W_*F_);
        #pragma unroll
        for (int r = 0; r < 16; ++r) {
            const int off2j = 2*(r & 3) + 16*(r >> 2);   // 2*j within quad
            ow[(size_t)off2j * (W_*F_)] = a2r[r] * scl + sft;
        }
    };

    bf16x8 GA[2][4], GBf[2][4];
    gload(GA, w0);
    #pragma unroll
    for (int wi = 0; wi < 8; ++wi) {
        if (wi & 1) {
            if (wi < 7) gload(GA, w0 + wi + 1);
            body(GBf, w0 + wi);
        } else {
            if (wi < 7) gload(GBf, w0 + wi + 1);
            body(GA, w0 + wi);
        }
    }
}

extern "C" void kernel_launch(void* const* d_in, const int* in_sizes, int n_in,
                              void* d_out, int out_size, void* d_ws, size_t ws_size,
                              hipStream_t stream)
{
    const float* x  = (const float*)d_in[0];
    const float* Wg = (const float*)d_in[1];
    const float* bg = (const float*)d_in[2];
    const float* Wt = (const float*)d_in[3];
    const float* bt = (const float*)d_in[4];
    const float* Wp = (const float*)d_in[5];
    const float* bp = (const float*)d_in[6];
    const float* Wo = (const float*)d_in[7];
    const float* bo = (const float*)d_in[8];
    const float* ga = (const float*)d_in[9];
    const float* be = (const float*)d_in[10];
    const float* mm = (const float*)d_in[11];
    const float* mv = (const float*)d_in[12];
    float* out = (float*)d_out;

    // ws layout: g 32MiB | Spart 32MiB (T1buf overlays; Spart dead after kR) |
    //            cspart 256KiB | U 256KiB | Sred 1MiB | csred 8KiB | T2buf 4KiB
    char* ws = (char*)d_ws;
    unsigned short* g = (unsigned short*)ws;
    size_t off = (size_t)B_ * N_ * F_ * sizeof(unsigned short);
    float* Spart = (float*)(ws + off);
    float* T1buf = (float*)(ws + off);
    off += (size_t)B_ * SPLITS * C_ * C_ * sizeof(float);
    float* cspart = (float*)(ws + off);
    off += (size_t)B_ * SPLITS * C_ * sizeof(float);
    float* U = (float*)(ws + off);
    off += (size_t)B_ * F_ * F_ * sizeof(float);
    float* Sred = (float*)(ws + off);
    off += (size_t)B_ * C_ * C_ * sizeof(float);
    float* csred = (float*)(ws + off);
    off += (size_t)B_ * C_ * sizeof(float);
    float* T2buf = (float*)(ws + off);

    kS<<<B_ * SPLITS, 256, 0, stream>>>(x, Wg, bg, g, Spart, cspart);
    kR<<<B_ * 16, 256, 0, stream>>>(Spart, cspart, Sred, csred);
    kT<<<B_ * 4, 256, 0, stream>>>(Sred, csred, Wp, T1buf, T2buf);
    kF<<<B_, 256, 0, stream>>>(T1buf, T2buf, csred, Wt, bt, bp, U);
    kC<<<B_ * 2 * (W_/8), 256, 0, stream>>>(g, U, Wo, bo, ga, be, mm, mv, out);
}

// Round 16
// 103.774 us; speedup vs baseline: 1.2582x; 1.0250x over previous
//
#include <hip/hip_runtime.h>
#include <stdint.h>

#define B_ 16
#define H_ 128
#define W_ 128
#define C_ 128
#define F_ 64
#define N_ (H_*W_)          // 16384
#define SPLITS 32
#define RPB (N_/SPLITS)     // 512 rows per block
#define CH 64               // rows per chunk in kS
#define NCH (RPB/CH)        // 8 chunks
#define EPSV 1e-3f

typedef __attribute__((ext_vector_type(8))) short bf16x8;
typedef __attribute__((ext_vector_type(16))) float f32x16;

__device__ __forceinline__ unsigned short f2b(float f) {
    unsigned int x = __float_as_uint(f);
    x += 0x7fffu + ((x >> 16) & 1u);
    return (unsigned short)(x >> 16);
}
__device__ __forceinline__ float b2f(unsigned short u) {
    return __uint_as_float(((unsigned int)u) << 16);
}

// ---------------------------------------------------------------------------
// Kernel S v10: v8 minus the xsT XOR swizzle (measured 6.68M bank-conflict
// cycles vs 2.1M unswizzled — the r12 bank model was wrong; isolating it).
// Keeps: register csum, post-barrier-B prefetch, gT coalesced g stores.
// ---------------------------------------------------------------------------
__global__ __launch_bounds__(256, 2)
void kS(const float* __restrict__ x, const float* __restrict__ Wg,
        const float* __restrict__ bg, unsigned short* __restrict__ g,
        float* __restrict__ Spart, float* __restrict__ cspart)
{
    __shared__ unsigned int  xsT_hi[C_][36];                   // 18 KiB
    __shared__ unsigned int  xsT_lo[C_][36];                   // 18 KiB
    __shared__ __align__(16) unsigned short xs_pool[CH][136];  // 17 KiB
    __shared__ __align__(16) unsigned short gT[CH][72];        //  9 KiB

    const int tid  = threadIdx.x;
    const int lane = tid & 63;
    const int w    = tid >> 6;
    const int b    = blockIdx.x >> 5;
    const int sp   = blockIdx.x & 31;

    const float* xb = x + ((size_t)b * N_ + (size_t)sp * RPB) * C_;
    unsigned short* gb = g + ((size_t)b * N_ + (size_t)sp * RPB) * F_;

    const int rowA = lane & 31;
    const int hiL  = lane >> 5;
    const int kgrp = hiL * 8;
    const int c1b  = (w & 1) * 64;
    const int c2b  = (w >> 1) * 64;
    const int nbG  = (w & 1) * 32;
    const int fbG  = (w >> 1) * 32;

    const float bgl = bg[fbG + rowA];

    for (int i = tid; i < C_*F_; i += 256) {
        int c = i >> 6, f = i & 63;
        xs_pool[f][c] = f2b(Wg[i]);
    }
    __syncthreads();
    bf16x8 wgfr[8];
    #pragma unroll
    for (int ks = 0; ks < 8; ++ks)
        wgfr[ks] = *(const bf16x8*)&xs_pool[fbG + rowA][ks*16 + kgrp];
    __syncthreads();   // frag reads done before pool becomes xs_hi

    f32x16 accS[2][2];
    #pragma unroll
    for (int ti = 0; ti < 2; ++ti)
        #pragma unroll
        for (int tj = 0; tj < 2; ++tj)
            #pragma unroll
            for (int e = 0; e < 16; ++e) accS[ti][tj][e] = 0.f;

    float4 csr[4];
    #pragma unroll
    for (int p = 0; p < 4; ++p) csr[p] = make_float4(0.f, 0.f, 0.f, 0.f);

    const int sr = tid >> 2;        // 0..63
    const int sc = (tid & 3) * 16;  // 0,16,32,48

    float4 ra[4], rq[4];
    auto loadChunk = [&](int ch) {
        const float* xc = xb + (size_t)ch * CH * C_;
        #pragma unroll
        for (int p = 0; p < 4; ++p) {
            const int idx = tid + 256*p;
            const float* r0 = xc + (size_t)(2*(idx & 31)) * C_ + ((idx >> 5) * 4);
            ra[p] = *(const float4*)r0;
            rq[p] = *(const float4*)(r0 + C_);
        }
    };

    loadChunk(0);

    for (int ch = 0; ch < NCH; ++ch) {
        __syncthreads();   // (A) prior readers done; drains this chunk's loads

        uint4 gv0, gv1;
        if (ch) {
            gv0 = *(const uint4*)&gT[sr][sc];
            gv1 = *(const uint4*)&gT[sr][sc + 8];
        }

        #pragma unroll
        for (int p = 0; p < 4; ++p) {
            const int idx = tid + 256*p;
            const int np  = idx & 31;
            const int c4  = (idx >> 5) * 4;
            float4 a = ra[p], q = rq[p];
            csr[p].x += a.x + q.x;
            csr[p].y += a.y + q.y;
            csr[p].z += a.z + q.z;
            csr[p].w += a.w + q.w;
            unsigned short ha0 = f2b(a.x), ha1 = f2b(a.y), ha2 = f2b(a.z), ha3 = f2b(a.w);
            unsigned short hb0 = f2b(q.x), hb1 = f2b(q.y), hb2 = f2b(q.z), hb3 = f2b(q.w);
            unsigned short la0 = f2b(a.x - b2f(ha0)), la1 = f2b(a.y - b2f(ha1));
            unsigned short la2 = f2b(a.z - b2f(ha2)), la3 = f2b(a.w - b2f(ha3));
            unsigned short lb0 = f2b(q.x - b2f(hb0)), lb1 = f2b(q.y - b2f(hb1));
            unsigned short lb2 = f2b(q.z - b2f(hb2)), lb3 = f2b(q.w - b2f(hb3));
            xsT_hi[c4+0][np] = (unsigned)ha0 | ((unsigned)hb0 << 16);
            xsT_hi[c4+1][np] = (unsigned)ha1 | ((unsigned)hb1 << 16);
            xsT_hi[c4+2][np] = (unsigned)ha2 | ((unsigned)hb2 << 16);
            xsT_hi[c4+3][np] = (unsigned)ha3 | ((unsigned)hb3 << 16);
            xsT_lo[c4+0][np] = (unsigned)la0 | ((unsigned)lb0 << 16);
            xsT_lo[c4+1][np] = (unsigned)la1 | ((unsigned)lb1 << 16);
            xsT_lo[c4+2][np] = (unsigned)la2 | ((unsigned)lb2 << 16);
            xsT_lo[c4+3][np] = (unsigned)la3 | ((unsigned)lb3 << 16);
            ushort4 u0; u0.x = ha0; u0.y = ha1; u0.z = ha2; u0.w = ha3;
            ushort4 u1; u1.x = hb0; u1.y = hb1; u1.z = hb2; u1.w = hb3;
            *(ushort4*)&xs_pool[2*np  ][c4] = u0;
            *(ushort4*)&xs_pool[2*np+1][c4] = u1;
        }

        if (ch) {
            unsigned short* dst = gb + (size_t)((ch-1)*CH + sr) * F_ + sc;
            *(uint4*)dst       = gv0;
            *(uint4*)(dst + 8) = gv1;
        }
        __syncthreads();   // (B) xsT/pool writes visible

        if (ch < NCH - 1) loadChunk(ch + 1);

        {
            f32x16 aG;
            #pragma unroll
            for (int e = 0; e < 16; ++e) aG[e] = 0.f;
            #pragma unroll
            for (int ks = 0; ks < 8; ++ks) {
                bf16x8 av = *(const bf16x8*)&xs_pool[nbG + rowA][ks*16 + kgrp];
                aG = __builtin_amdgcn_mfma_f32_32x32x16_bf16(av, wgfr[ks], aG, 0, 0, 0);
            }
            const int fcol = fbG + rowA;
            #pragma unroll
            for (int r = 0; r < 16; ++r) {
                int nloc = (r & 3) + 8*(r >> 2) + 4*hiL;
                gT[nbG + nloc][fcol] = f2b(aG[r] + bgl);
            }
        }

        #pragma unroll
        for (int ks = 0; ks < 4; ++ks) {
            const int kn = ks*16 + kgrp;
            bf16x8 Ah[2], Al[2], Bh[2], Bl[2];
            #pragma unroll
            for (int t = 0; t < 2; ++t) {
                const unsigned short* rAh = (const unsigned short*)&xsT_hi[c1b + 32*t + rowA][0];
                const unsigned short* rAl = (const unsigned short*)&xsT_lo[c1b + 32*t + rowA][0];
                Ah[t] = *(const bf16x8*)(rAh + kn);
                Al[t] = *(const bf16x8*)(rAl + kn);
                const unsigned short* rBh = (const unsigned short*)&xsT_hi[c2b + 32*t + rowA][0];
                const unsigned short* rBl = (const unsigned short*)&xsT_lo[c2b + 32*t + rowA][0];
                Bh[t] = *(const bf16x8*)(rBh + kn);
                Bl[t] = *(const bf16x8*)(rBl + kn);
            }
            #pragma unroll
            for (int ti = 0; ti < 2; ++ti)
                #pragma unroll
                for (int tj = 0; tj < 2; ++tj) {
                    accS[ti][tj] = __builtin_amdgcn_mfma_f32_32x32x16_bf16(Ah[ti], Bh[tj], accS[ti][tj], 0, 0, 0);
                    accS[ti][tj] = __builtin_amdgcn_mfma_f32_32x32x16_bf16(Ah[ti], Bl[tj], accS[ti][tj], 0, 0, 0);
                    accS[ti][tj] = __builtin_amdgcn_mfma_f32_32x32x16_bf16(Al[ti], Bh[tj], accS[ti][tj], 0, 0, 0);
                }
        }
    }

    __syncthreads();
    {
        uint4 gv0 = *(const uint4*)&gT[sr][sc];
        uint4 gv1 = *(const uint4*)&gT[sr][sc + 8];
        unsigned short* dst = gb + (size_t)((NCH - 1)*CH + sr) * F_ + sc;
        *(uint4*)dst       = gv0;
        *(uint4*)(dst + 8) = gv1;
    }

    float* so = Spart + (size_t)(b * SPLITS + sp) * (size_t)(C_ * C_);
    #pragma unroll
    for (int ti = 0; ti < 2; ++ti)
        #pragma unroll
        for (int tj = 0; tj < 2; ++tj)
            #pragma unroll
            for (int r = 0; r < 16; ++r) {
                int c1 = c1b + 32*ti + (r & 3) + 8*(r >> 2) + 4*hiL;
                int c2 = c2b + 32*tj + rowA;
                so[(size_t)c1 * C_ + c2] = accS[ti][tj][r];
            }

    #pragma unroll
    for (int p = 0; p < 4; ++p) {
        #pragma unroll
        for (int o = 16; o; o >>= 1) {
            csr[p].x += __shfl_xor(csr[p].x, o);
            csr[p].y += __shfl_xor(csr[p].y, o);
            csr[p].z += __shfl_xor(csr[p].z, o);
            csr[p].w += __shfl_xor(csr[p].w, o);
        }
    }
    if ((lane & 31) == 0) {
        const int h = lane >> 5;
        float* co = cspart + (size_t)(b * SPLITS + sp) * C_;
        #pragma unroll
        for (int p = 0; p < 4; ++p) {
            const int c4 = 4 * (2*w + h + 8*p);
            co[c4+0] = csr[p].x;
            co[c4+1] = csr[p].y;
            co[c4+2] = csr[p].z;
            co[c4+3] = csr[p].w;
        }
    }
}

// ---------------------------------------------------------------------------
// Kernel R: reduce Spart over splits -> Sred ; cspart -> csred. Pure BW.
// ---------------------------------------------------------------------------
__global__ __launch_bounds__(256, 8)
void kR(const float* __restrict__ Spart, const float* __restrict__ cspart,
        float* __restrict__ Sred, float* __restrict__ csred)
{
    const int b = blockIdx.x >> 4;
    const int r = blockIdx.x & 15;
    const int f4 = r*256 + threadIdx.x;
    const float4* base = (const float4*)(Spart + (size_t)b * SPLITS * C_ * C_);
    float sx=0.f, sy=0.f, sz=0.f, sw=0.f;
    #pragma unroll 4
    for (int sp = 0; sp < SPLITS; ++sp) {
        float4 v = base[(size_t)sp * (C_*C_/4) + f4];
        sx += v.x; sy += v.y; sz += v.z; sw += v.w;
    }
    ((float4*)(Sred + (size_t)b * C_ * C_))[f4] = make_float4(sx, sy, sz, sw);

    if (r == 0 && threadIdx.x < C_) {
        float c = 0.f;
        #pragma unroll 4
        for (int sp = 0; sp < SPLITS; ++sp)
            c += cspart[((size_t)b * SPLITS + sp) * C_ + threadIdx.x];
        csred[(size_t)b * C_ + threadIdx.x] = c;
    }
}

// ---------------------------------------------------------------------------
// Kernel T: T1 = S @ Wp (per-batch 128x64, K=128), LDS-staged; also T2 = cs@Wp.
// ---------------------------------------------------------------------------
__global__ __launch_bounds__(256, 2)
void kT(const float* __restrict__ Sred, const float* __restrict__ csred,
        const float* __restrict__ Wp, float* __restrict__ T1buf,
        float* __restrict__ T2buf)
{
    __shared__ float Ss[32][C_];
    __shared__ float Wps[C_][F_];

    const int tid = threadIdx.x;
    const int b = blockIdx.x >> 2;
    const int q = blockIdx.x & 3;

    const float4* sg = (const float4*)(Sred + ((size_t)b * C_ + q*32) * C_);
    for (int t = tid; t < 32*C_/4; t += 256) ((float4*)Ss)[t] = sg[t];
    const float4* wg = (const float4*)Wp;
    for (int t = tid; t < C_*F_/4; t += 256) ((float4*)Wps)[t] = wg[t];
    __syncthreads();

    const int lane = tid & 63;
    const int w    = tid >> 6;

    float acc[8] = {0.f,0.f,0.f,0.f,0.f,0.f,0.f,0.f};
    #pragma unroll 2
    for (int k = 0; k < C_; k += 4) {
        float w0 = Wps[k+0][lane];
        float w1 = Wps[k+1][lane];
        float w2 = Wps[k+2][lane];
        float w3 = Wps[k+3][lane];
        #pragma unroll
        for (int cl = 0; cl < 8; ++cl) {
            float4 sv = *(const float4*)&Ss[w*8 + cl][k];
            float t = acc[cl];
            t = fmaf(sv.x, w0, t);
            t = fmaf(sv.y, w1, t);
            t = fmaf(sv.z, w2, t);
            t = fmaf(sv.w, w3, t);
            acc[cl] = t;
        }
    }
    #pragma unroll
    for (int cl = 0; cl < 8; ++cl) {
        int c = q*32 + w*8 + cl;
        T1buf[((size_t)b * C_ + c) * F_ + lane] = acc[cl];
    }

    if (q == 0 && tid < F_) {
        const float* cv = csred + (size_t)b * C_;
        float s = 0.f;
        for (int k = 0; k < C_; ++k) s = fmaf(cv[k], Wps[k][tid], s);
        T2buf[(size_t)b * F_ + tid] = s;
    }
}

// ---------------------------------------------------------------------------
// Kernel F: fm = Wt^T T1 + bias terms; in-register row softmax -> U.
// ---------------------------------------------------------------------------
__global__ __launch_bounds__(256, 2)
void kF(const float* __restrict__ T1buf, const float* __restrict__ T2buf,
        const float* __restrict__ csred, const float* __restrict__ Wt,
        const float* __restrict__ bt, const float* __restrict__ bp,
        float* __restrict__ U)
{
    __shared__ float T1s[C_][F_];
    __shared__ float Wts[C_][F_];
    __shared__ float csb[C_];
    __shared__ float T2s[F_], T3s[F_], bts[F_], bps[F_];

    const int tid = threadIdx.x;
    const int b = blockIdx.x;

    for (int t = tid; t < C_*F_/4; t += 256) {
        ((float4*)T1s)[t] = ((const float4*)(T1buf + (size_t)b * C_ * F_))[t];
        ((float4*)Wts)[t] = ((const float4*)Wt)[t];
    }
    if (tid < C_) csb[tid] = csred[(size_t)b * C_ + tid];
    if (tid < F_) {
        T2s[tid] = T2buf[(size_t)b * F_ + tid];
        bts[tid] = bt[tid];
        bps[tid] = bp[tid];
    }
    __syncthreads();

    if (tid < F_) {
        float s = 0.f;
        for (int c = 0; c < C_; ++c) s = fmaf(csb[c], Wts[c][tid], s);
        T3s[tid] = s;
    }
    __syncthreads();

    const int lane = tid & 63;
    const int w    = tid >> 6;

    float acc[16];
    #pragma unroll
    for (int r = 0; r < 16; ++r) acc[r] = 0.f;

    #pragma unroll 2
    for (int c = 0; c < C_; ++c) {
        float t1 = T1s[c][lane];
        #pragma unroll
        for (int u = 0; u < 4; ++u) {
            float4 wv = *(const float4*)&Wts[c][w*16 + u*4];
            acc[u*4+0] = fmaf(wv.x, t1, acc[u*4+0]);
            acc[u*4+1] = fmaf(wv.y, t1, acc[u*4+1]);
            acc[u*4+2] = fmaf(wv.z, t1, acc[u*4+2]);
            acc[u*4+3] = fmaf(wv.w, t1, acc[u*4+3]);
        }
    }

    const float bpj = bps[lane];
    const float t2j = T2s[lane];
    #pragma unroll
    for (int r = 0; r < 16; ++r) {
        const int i = w*16 + r;
        float v = acc[r] + T3s[i]*bpj + bts[i]*(t2j + (float)N_ * bpj);
        float m = v;
        #pragma unroll
        for (int o = 32; o; o >>= 1) m = fmaxf(m, __shfl_xor(m, o));
        float e = expf(v - m);
        float s = e;
        #pragma unroll
        for (int o = 32; o; o >>= 1) s += __shfl_xor(s, o);
        U[((size_t)b * F_ + i) * F_ + lane] = e / s;
    }
}

// ---------------------------------------------------------------------------
// Kernel C (MFMA, barrier-free bodies): per (b,half,w): M1 = G_w @ U ;
// Out = M1^T @ Wo ; bias+BN fused. M1T strip is wave-private.
// ---------------------------------------------------------------------------
__global__ __launch_bounds__(256, 2)
void kC(const unsigned short* __restrict__ g, const float* __restrict__ U,
        const float* __restrict__ Wo, const float* __restrict__ bo,
        const float* __restrict__ gamma_, const float* __restrict__ beta_,
        const float* __restrict__ mmean, const float* __restrict__ mvar,
        float* __restrict__ out)
{
    __shared__ __align__(16) unsigned short UT[F_][72];        // UT[j][i] bf16
    __shared__ __align__(16) unsigned short WoT[F_][72];       // WoT[e'][f] bf16
    __shared__ __align__(16) unsigned short M1T[4][32][72];    // per-wave M1^T[j][e]

    const int tid  = threadIdx.x;
    const int lane = tid & 63;
    const int wv   = tid >> 6;
    const int jt   = wv & 1;
    const int et   = wv >> 1;

    const int wgrp = blockIdx.x & 15;
    const int half = (blockIdx.x >> 4) & 1;
    const int b    = blockIdx.x >> 5;

    for (int t = tid; t < 1024; t += 256) {
        const int i  = t >> 4;
        const int j4 = (t & 15) * 4;
        float4 uv = *(const float4*)(U + ((size_t)b * F_ + i) * F_ + j4);
        UT[j4+0][i] = f2b(uv.x); UT[j4+1][i] = f2b(uv.y);
        UT[j4+2][i] = f2b(uv.z); UT[j4+3][i] = f2b(uv.w);
        float4 wo4 = *(const float4*)(Wo + (size_t)i * F_ + j4);
        WoT[j4+0][i] = f2b(wo4.x); WoT[j4+1][i] = f2b(wo4.y);
        WoT[j4+2][i] = f2b(wo4.z); WoT[j4+3][i] = f2b(wo4.w);
    }
    __syncthreads();

    const int rowA = lane & 31;
    const int hi   = lane >> 5;
    const int hi8  = hi * 8;

    bf16x8 Ufr[4], WoFr[4];
    #pragma unroll
    for (int ks = 0; ks < 4; ++ks) {
        Ufr[ks]  = *(const bf16x8*)&UT [32*jt + rowA][16*ks + hi8];
        WoFr[ks] = *(const bf16x8*)&WoT[32*et + rowA][16*ks + hi8];
    }

    const int ep = 32*et + rowA;                 // this lane's output channel
    const float scl = gamma_[ep] * rsqrtf(mvar[ep] + EPSV);
    const float sft = (bo[ep] - mmean[ep]) * scl + beta_[ep];

    const unsigned short* gB = g + ((size_t)b * N_ + (size_t)half * (N_/2)) * F_;
    float* outB = out + (((size_t)b * H_ + half) * W_) * F_ + ep;
    const int w0 = wgrp * 8;

    unsigned short* m1row = &M1T[wv][rowA][0];

    auto gload = [&](bf16x8 (&D)[2][4], int widx) {
        const unsigned short* gw = gB + (size_t)widx * (64*F_) + (size_t)rowA * F_ + hi8;
        #pragma unroll
        for (int ft = 0; ft < 2; ++ft)
            #pragma unroll
            for (int ks = 0; ks < 4; ++ks)
                D[ft][ks] = *(const bf16x8*)(gw + ft*(32*F_) + 16*ks);
    };

    auto body = [&](bf16x8 (&G)[2][4], int widx) {
        f32x16 m0, m1, a2r;
        #pragma unroll
        for (int e = 0; e < 16; ++e) { m0[e] = 0.f; m1[e] = 0.f; a2r[e] = 0.f; }
        #pragma unroll
        for (int ks = 0; ks < 4; ++ks) {
            m0 = __builtin_amdgcn_mfma_f32_32x32x16_bf16(G[0][ks], Ufr[ks], m0, 0, 0, 0);
            m1 = __builtin_amdgcn_mfma_f32_32x32x16_bf16(G[1][ks], Ufr[ks], m1, 0, 0, 0);
        }
        #pragma unroll
        for (int r = 0; r < 16; r += 2) {
            const int e0 = (r & 3) + 8*(r >> 2) + 4*hi;
            const unsigned pw0 = (unsigned)f2b(m0[r]) | ((unsigned)f2b(m0[r+1]) << 16);
            *(unsigned int*)(m1row + e0) = pw0;
            const unsigned pw1 = (unsigned)f2b(m1[r]) | ((unsigned)f2b(m1[r+1]) << 16);
            *(unsigned int*)(m1row + 32 + e0) = pw1;
        }
        #pragma unroll
        for (int ksg = 0; ksg < 4; ++ksg) {
            bf16x8 af = *(const bf16x8*)(m1row + 16*ksg + hi8);
            a2r = __builtin_amdgcn_mfma_f32_32x32x16_bf16(af, WoFr[ksg], a2r, 0, 0, 0);
        }
        float* ow = outB + (size_t)widx * F_ + (size_t)(64*jt + 8*hi) * (W_*F_);
        #pragma unroll
        for (int r = 0; r < 16; ++r) {
            const int off2j = 2*(r & 3) + 16*(r >> 2);   // 2*j within quad
            ow[(size_t)off2j * (W_*F_)] = a2r[r] * scl + sft;
        }
    };

    bf16x8 GA[2][4], GBf[2][4];
    gload(GA, w0);
    #pragma unroll
    for (int wi = 0; wi < 8; ++wi) {
        if (wi & 1) {
            if (wi < 7) gload(GA, w0 + wi + 1);
            body(GBf, w0 + wi);
        } else {
            if (wi < 7) gload(GBf, w0 + wi + 1);
            body(GA, w0 + wi);
        }
    }
}

extern "C" void kernel_launch(void* const* d_in, const int* in_sizes, int n_in,
                              void* d_out, int out_size, void* d_ws, size_t ws_size,
                              hipStream_t stream)
{
    const float* x  = (const float*)d_in[0];
    const float* Wg = (const float*)d_in[1];
    const float* bg = (const float*)d_in[2];
    const float* Wt = (const float*)d_in[3];
    const float* bt = (const float*)d_in[4];
    const float* Wp = (const float*)d_in[5];
    const float* bp = (const float*)d_in[6];
    const float* Wo = (const float*)d_in[7];
    const float* bo = (const float*)d_in[8];
    const float* ga = (const float*)d_in[9];
    const float* be = (const float*)d_in[10];
    const float* mm = (const float*)d_in[11];
    const float* mv = (const float*)d_in[12];
    float* out = (float*)d_out;

    // ws layout: g 32MiB | Spart 32MiB (T1buf overlays; Spart dead after kR) |
    //            cspart 256KiB | U 256KiB | Sred 1MiB | csred 8KiB | T2buf 4KiB
    char* ws = (char*)d_ws;
    unsigned short* g = (unsigned short*)ws;
    size_t off = (size_t)B_ * N_ * F_ * sizeof(unsigned short);
    float* Spart = (float*)(ws + off);
    float* T1buf = (float*)(ws + off);
    off += (size_t)B_ * SPLITS * C_ * C_ * sizeof(float);
    float* cspart = (float*)(ws + off);
    off += (size_t)B_ * SPLITS * C_ * sizeof(float);
    float* U = (float*)(ws + off);
    off += (size_t)B_ * F_ * F_ * sizeof(float);
    float* Sred = (float*)(ws + off);
    off += (size_t)B_ * C_ * C_ * sizeof(float);
    float* csred = (float*)(ws + off);
    off += (size_t)B_ * C_ * sizeof(float);
    float* T2buf = (float*)(ws + off);

    kS<<<B_ * SPLITS, 256, 0, stream>>>(x, Wg, bg, g, Spart, cspart);
    kR<<<B_ * 16, 256, 0, stream>>>(Spart, cspart, Sred, csred);
    kT<<<B_ * 4, 256, 0, stream>>>(Sred, csred, Wp, T1buf, T2buf);
    kF<<<B_, 256, 0, stream>>>(T1buf, T2buf, csred, Wt, bt, bp, U);
    kC<<<B_ * 2 * (W_/8), 256, 0, stream>>>(g, U, Wo, bo, ga, be, mm, mv, out);
}